// Round 6
// baseline (174.447 us; speedup 1.0000x reference)
//
#include <hip/hip_runtime.h>
#include <hip/hip_cooperative_groups.h>

namespace cg = cooperative_groups;

#define NEG_SLOPE 0.01f

constexpr int N = 8192;
constexpr int D = 64;
constexpr int RB = 16;        // rows per block
constexpr int NB = N / RB;    // 512 blocks = 2 blocks/CU

typedef __bf16 bf16x8 __attribute__((ext_vector_type(8)));
typedef float f32x4 __attribute__((ext_vector_type(4)));

// ============ single fused cooperative kernel ============
// Phase A: w1/w2 = W^T a1/a2, c = b·a; s1/s2 for this block's 16 rows;
//          per-block max(s1) (plain store -> no memset dispatch needed);
//          pack this block's 16 rows of x into bf16 MFMA B-fragments.
// grid.sync()  (threadfence = agent-scope release; sync acquires)
// Phase C: flash aggregation out = softmax(P)·x on MFMA, Z in f32 regs.
__global__ __launch_bounds__(256, 2) void gat_fused(
    const float* __restrict__ x, const float* __restrict__ W_,
    const float* __restrict__ b, const float* __restrict__ a,
    float* __restrict__ s1g, float* __restrict__ blockmax,
    bf16x8* __restrict__ xf, float* __restrict__ out) {
  __shared__ float w1s[D], w2s[D], cs[2];
  __shared__ float s1loc[RB], s2loc[RB];
  __shared__ float wred[4];
  __shared__ float accT[4][RB][64];
  __shared__ float zt[4][RB];

  const int t = threadIdx.x;
  const int bid = blockIdx.x;
  const int lane = t & 63;
  const int w = t >> 6;

  // ---- A1: attention-vector projections (redundant per block, 16KB W L2-hot)
  if (t < 128) {
    const int sel = t >> 6, d = t & 63;
    const float* av = a + sel * D;
    float acc = 0.f;
#pragma unroll
    for (int k = 0; k < D; ++k) acc += W_[k * D + d] * av[k];
    (sel ? w2s : w1s)[d] = acc;
  }
  if (t == 128 || t == 129) {
    const int sel = t - 128;
    float acc = 0.f;
    for (int d = 0; d < D; ++d) acc += b[d] * a[sel * D + d];
    cs[sel] = acc;
  }
  __syncthreads();

  // ---- A2: s1/s2 for rows bid*16..+15 (16 threads per row, shfl reduce)
  {
    const int r = t >> 4, seg = t & 15;
    const int gi = bid * RB + r;
    const float4 xv = *(const float4*)(x + (size_t)gi * D + seg * 4);
    float p1 = xv.x * w1s[seg * 4 + 0] + xv.y * w1s[seg * 4 + 1] +
               xv.z * w1s[seg * 4 + 2] + xv.w * w1s[seg * 4 + 3];
    float p2 = xv.x * w2s[seg * 4 + 0] + xv.y * w2s[seg * 4 + 1] +
               xv.z * w2s[seg * 4 + 2] + xv.w * w2s[seg * 4 + 3];
#pragma unroll
    for (int off = 8; off; off >>= 1) {
      p1 += __shfl_xor(p1, off, 64);
      p2 += __shfl_xor(p2, off, 64);
    }
    if (seg == 0) {
      const float v1 = p1 + cs[0], v2 = p2 + cs[1];
      s1g[gi] = v1;
      s1loc[r] = v1;
      s2loc[r] = v2;
    }
  }

  // ---- A3: pack this block's 16 rows into B-frags.
  // xf[gid], gid=(window<<8)|(dt<<6)|fl holds bf16 x[window*32+(fl>>4)*8+q][dt*16+(fl&15)]
  if (t < 128) {
    const int h = bid & 1, w0 = bid >> 1;
    const int dt = t >> 5, ll = t & 31;
    const int fl = h * 32 + ll;
    const int jb = w0 * 32 + ((fl >> 4) << 3);
    const int col = dt * 16 + (fl & 15);
    bf16x8 f;
#pragma unroll
    for (int q = 0; q < 8; ++q) f[q] = (__bf16)x[(size_t)(jb + q) * D + col];
    xf[(w0 << 8) | (dt << 6) | fl] = f;
  }
  __syncthreads();
  if (t == 0) {
    float m = s1loc[0];
#pragma unroll
    for (int r = 1; r < RB; ++r) m = fmaxf(m, s1loc[r]);
    blockmax[bid] = m;
  }

  __threadfence();          // agent-scope release (L2 writeback on gfx950)
  cg::this_grid().sync();   // grid barrier + acquire

  // ---- global max(s1) from blockmax[512]
  float gm;
  {
    float v = fmaxf(blockmax[t], blockmax[t + 256]);
#pragma unroll
    for (int off = 32; off; off >>= 1) v = fmaxf(v, __shfl_xor(v, off, 64));
    if (lane == 0) wred[w] = v;
    __syncthreads();
    gm = fmaxf(fmaxf(wred[0], wred[1]), fmaxf(wred[2], wred[3]));
  }

  // ---- Phase C: MFMA flash aggregation (16 rows, 4 waves split j-range)
  const int arow = lane & 15;  // M index within tile
  const int grp = lane >> 4;   // k-group
  const float s2v = s2loc[arow];
  const float tmax = s2v + gm;
  const float mneg = -fmaxf(tmax, NEG_SLOPE * tmax);  // -m_i (leaky monotone)

  f32x4 acc0 = {0.f, 0.f, 0.f, 0.f};
  f32x4 acc1 = {0.f, 0.f, 0.f, 0.f};
  f32x4 acc2 = {0.f, 0.f, 0.f, 0.f};
  f32x4 acc3 = {0.f, 0.f, 0.f, 0.f};
  float zz = 0.f;

#pragma unroll 2
  for (int c = w; c < N / 32; c += 4) {
    const int fb = c << 8;
    bf16x8 xb0 = xf[fb + 0 * 64 + lane];
    bf16x8 xb1 = xf[fb + 1 * 64 + lane];
    bf16x8 xb2 = xf[fb + 2 * 64 + lane];
    bf16x8 xb3 = xf[fb + 3 * 64 + lane];

    const float* s1p = s1g + c * 32 + grp * 8;
    const float4 sa = *(const float4*)s1p;
    const float4 sb = *(const float4*)(s1p + 4);

    float pv[8];
    {
      const float* sv = &sa.x;
#pragma unroll
      for (int q = 0; q < 4; ++q) {
        const float tt = s2v + sv[q];
        pv[q] = __expf(fmaxf(tt, NEG_SLOPE * tt) + mneg);
      }
      const float* sw = &sb.x;
#pragma unroll
      for (int q = 0; q < 4; ++q) {
        const float tt = s2v + sw[q];
        pv[4 + q] = __expf(fmaxf(tt, NEG_SLOPE * tt) + mneg);
      }
    }
    bf16x8 pa;
#pragma unroll
    for (int q = 0; q < 8; ++q) {
      pa[q] = (__bf16)pv[q];
      zz += pv[q];
    }

    acc0 = __builtin_amdgcn_mfma_f32_16x16x32_bf16(pa, xb0, acc0, 0, 0, 0);
    acc1 = __builtin_amdgcn_mfma_f32_16x16x32_bf16(pa, xb1, acc1, 0, 0, 0);
    acc2 = __builtin_amdgcn_mfma_f32_16x16x32_bf16(pa, xb2, acc2, 0, 0, 0);
    acc3 = __builtin_amdgcn_mfma_f32_16x16x32_bf16(pa, xb3, acc3, 0, 0, 0);
  }

  // Z: sum the 4 k-group lanes of each row
  zz += __shfl_xor(zz, 16, 64);
  zz += __shfl_xor(zz, 32, 64);
  if (lane < 16) zt[w][lane] = zz;

  // C/D frag -> LDS: out-row = grp*4+reg, out-col = dt*16 + arow
#pragma unroll
  for (int reg = 0; reg < 4; ++reg) {
    accT[w][grp * 4 + reg][0 * 16 + arow] = acc0[reg];
    accT[w][grp * 4 + reg][1 * 16 + arow] = acc1[reg];
    accT[w][grp * 4 + reg][2 * 16 + arow] = acc2[reg];
    accT[w][grp * 4 + reg][3 * 16 + arow] = acc3[reg];
  }
  __syncthreads();

#pragma unroll
  for (int k = 0; k < 4; ++k) {
    const int r = w * 4 + k;
    const float s = accT[0][r][lane] + accT[1][r][lane] + accT[2][r][lane] + accT[3][r][lane];
    const float z = zt[0][r] + zt[1][r] + zt[2][r] + zt[3][r];
    out[(size_t)(bid * RB + r) * D + lane] = s / z;
  }
}

extern "C" void kernel_launch(void* const* d_in, const int* in_sizes, int n_in,
                              void* d_out, int out_size, void* d_ws, size_t ws_size,
                              hipStream_t stream) {
  const float* x = (const float*)d_in[0];   // 8192*64 f32
  const float* W = (const float*)d_in[1];   // 64*64
  const float* b = (const float*)d_in[2];   // 64
  const float* a = (const float*)d_in[3];   // 128

  // ws: s1[8192] | blockmax[512] | @1MB: xf (1MB bf16 frags)
  float* s1 = (float*)d_ws;
  float* blockmax = s1 + N;
  bf16x8* xf = (bf16x8*)((char*)d_ws + (1u << 20));
  float* out = (float*)d_out;

  void* args[] = {(void*)&x, (void*)&W, (void*)&b, (void*)&a,
                  (void*)&s1, (void*)&blockmax, (void*)&xf, (void*)&out};
  hipLaunchCooperativeKernel((void*)gat_fused, dim3(NB), dim3(256), args, 0, stream);
}

// Round 7
// 88.901 us; speedup vs baseline: 1.9623x; 1.9623x over previous
//
#include <hip/hip_runtime.h>

#define NEG_SLOPE 0.01f

constexpr int N = 8192;
constexpr int D = 64;
constexpr int PB = 32;   // rows per prep block == j-window span packed by that block
constexpr int RB = 32;   // rows per main block

typedef __bf16 bf16x8 __attribute__((ext_vector_type(8)));
typedef float f32x4 __attribute__((ext_vector_type(4)));

// ---------------- K1: s1/s2 + per-block max + bf16 fragment pack ----------------
// 256 blocks x 256 threads; block bid owns rows [bid*32, bid*32+32) which is
// exactly pack-window bid (j = bid*32..+31), so x rows are L1-hot for the pack.
__global__ __launch_bounds__(256) void gat_prep(
    const float* __restrict__ x, const float* __restrict__ W_,
    const float* __restrict__ b, const float* __restrict__ a,
    float* __restrict__ s1g, float* __restrict__ s2g,
    float* __restrict__ blockmax, bf16x8* __restrict__ xf) {
  __shared__ float w1s[D], w2s[D], cs[2];
  __shared__ float s1loc[PB];

  const int t = threadIdx.x;
  const int bid = blockIdx.x;

  // A1: w1/w2 = W^T a1/a2 (redundant per block; W is 16KB, L2-hot)
  if (t < 128) {
    const int sel = t >> 6, d = t & 63;
    const float* av = a + sel * D;
    float acc = 0.f;
#pragma unroll
    for (int k = 0; k < D; ++k) acc += W_[k * D + d] * av[k];
    (sel ? w2s : w1s)[d] = acc;
  }
  if (t == 128 || t == 129) {
    const int sel = t - 128;
    float acc = 0.f;
    for (int d = 0; d < D; ++d) acc += b[d] * a[sel * D + d];
    cs[sel] = acc;
  }
  __syncthreads();

  // A2: s1/s2 for 32 rows; 8 threads per row, shfl-reduce within 8-lane groups
  {
    const int r = t >> 3, seg = t & 7;
    const int gi = bid * PB + r;
    const float4 xa = *(const float4*)(x + (size_t)gi * D + seg * 8);
    const float4 xb = *(const float4*)(x + (size_t)gi * D + seg * 8 + 4);
    float p1 = xa.x * w1s[seg * 8 + 0] + xa.y * w1s[seg * 8 + 1] +
               xa.z * w1s[seg * 8 + 2] + xa.w * w1s[seg * 8 + 3] +
               xb.x * w1s[seg * 8 + 4] + xb.y * w1s[seg * 8 + 5] +
               xb.z * w1s[seg * 8 + 6] + xb.w * w1s[seg * 8 + 7];
    float p2 = xa.x * w2s[seg * 8 + 0] + xa.y * w2s[seg * 8 + 1] +
               xa.z * w2s[seg * 8 + 2] + xa.w * w2s[seg * 8 + 3] +
               xb.x * w2s[seg * 8 + 4] + xb.y * w2s[seg * 8 + 5] +
               xb.z * w2s[seg * 8 + 6] + xb.w * w2s[seg * 8 + 7];
#pragma unroll
    for (int off = 4; off; off >>= 1) {
      p1 += __shfl_xor(p1, off, 64);
      p2 += __shfl_xor(p2, off, 64);
    }
    if (seg == 0) {
      const float v1 = p1 + cs[0], v2 = p2 + cs[1];
      s1g[gi] = v1;
      s2g[gi] = v2;
      s1loc[r] = v1;
    }
  }

  // A3: pack window bid into B-frags (x rows L1-hot from A2).
  // xf[gid], gid=(bid<<8)|(dt<<6)|fl holds bf16 x[bid*32+(fl>>4)*8+q][dt*16+(fl&15)]
  {
    const int dt = t >> 6, fl = t & 63;
    const int jb = bid * PB + ((fl >> 4) << 3);
    const int col = dt * 16 + (fl & 15);
    bf16x8 f;
#pragma unroll
    for (int q = 0; q < 8; ++q) f[q] = (__bf16)x[(size_t)(jb + q) * D + col];
    xf[(bid << 8) | (dt << 6) | fl] = f;
  }
  __syncthreads();
  if (t == 0) {
    float m = s1loc[0];
#pragma unroll
    for (int r = 1; r < PB; ++r) m = fmaxf(m, s1loc[r]);
    blockmax[bid] = m;
  }
}

// ---------------- K2: MFMA flash aggregation ----------------
// 256 blocks x 256 threads (4 waves), 32 rows/block: two A-frags per wave
// share the same 4 B-frags -> 8 MFMA per 4 dwordx4 loads; register
// double-buffer on B-frags + s1 so loads never chain into the MFMA sequence.
__global__ __launch_bounds__(256, 2) void gat_main(
    const bf16x8* __restrict__ xf, const float* __restrict__ s1g,
    const float* __restrict__ s2g, const float* __restrict__ blockmax,
    float* __restrict__ out) {
  __shared__ float accT[4][RB][64];  // 32KB
  __shared__ float zt[4][RB];
  __shared__ float gms;

  const int t = threadIdx.x;
  const int lane = t & 63;
  const int w = t >> 6;
  const int arow = lane & 15;
  const int grp = lane >> 4;
  const int ibase = blockIdx.x * RB;

  // global max(s1) from blockmax[256]
  if (w == 0) {
    float v = fmaxf(fmaxf(blockmax[lane], blockmax[lane + 64]),
                    fmaxf(blockmax[lane + 128], blockmax[lane + 192]));
#pragma unroll
    for (int off = 32; off; off >>= 1) v = fmaxf(v, __shfl_xor(v, off, 64));
    if (lane == 0) gms = v;
  }
  __syncthreads();
  const float gm = gms;

  const float s2v0 = s2g[ibase + arow];
  const float s2v1 = s2g[ibase + 16 + arow];
  const float tm0 = s2v0 + gm, tm1 = s2v1 + gm;
  const float mneg0 = -fmaxf(tm0, NEG_SLOPE * tm0);
  const float mneg1 = -fmaxf(tm1, NEG_SLOPE * tm1);

  f32x4 a00 = {0.f, 0.f, 0.f, 0.f}, a01 = a00, a02 = a00, a03 = a00;
  f32x4 a10 = a00, a11 = a00, a12 = a00, a13 = a00;
  float zz0 = 0.f, zz1 = 0.f;

  int c = w;
  bf16x8 xb0 = xf[(c << 8) + 0 * 64 + lane];
  bf16x8 xb1 = xf[(c << 8) + 1 * 64 + lane];
  bf16x8 xb2 = xf[(c << 8) + 2 * 64 + lane];
  bf16x8 xb3 = xf[(c << 8) + 3 * 64 + lane];
  float4 sa = *(const float4*)(s1g + c * 32 + grp * 8);
  float4 sb = *(const float4*)(s1g + c * 32 + grp * 8 + 4);

  for (int i = 0; i < N / 32 / 4; ++i) {
    const int cn = (i == N / 32 / 4 - 1) ? c : c + 4;  // last iter: dummy reload
    bf16x8 nb0 = xf[(cn << 8) + 0 * 64 + lane];
    bf16x8 nb1 = xf[(cn << 8) + 1 * 64 + lane];
    bf16x8 nb2 = xf[(cn << 8) + 2 * 64 + lane];
    bf16x8 nb3 = xf[(cn << 8) + 3 * 64 + lane];
    const float4 na = *(const float4*)(s1g + cn * 32 + grp * 8);
    const float4 nbb = *(const float4*)(s1g + cn * 32 + grp * 8 + 4);

    // P-frags for both row groups (exp in f32, cast bf16; Z from f32)
    bf16x8 pa0, pa1;
    {
      const float* sv = &sa.x;
#pragma unroll
      for (int q = 0; q < 4; ++q) {
        const float t0 = s2v0 + sv[q];
        const float p0 = __expf(fmaxf(t0, NEG_SLOPE * t0) + mneg0);
        zz0 += p0;
        pa0[q] = (__bf16)p0;
        const float t1 = s2v1 + sv[q];
        const float p1 = __expf(fmaxf(t1, NEG_SLOPE * t1) + mneg1);
        zz1 += p1;
        pa1[q] = (__bf16)p1;
      }
      const float* sw = &sb.x;
#pragma unroll
      for (int q = 0; q < 4; ++q) {
        const float t0 = s2v0 + sw[q];
        const float p0 = __expf(fmaxf(t0, NEG_SLOPE * t0) + mneg0);
        zz0 += p0;
        pa0[4 + q] = (__bf16)p0;
        const float t1 = s2v1 + sw[q];
        const float p1 = __expf(fmaxf(t1, NEG_SLOPE * t1) + mneg1);
        zz1 += p1;
        pa1[4 + q] = (__bf16)p1;
      }
    }

    a00 = __builtin_amdgcn_mfma_f32_16x16x32_bf16(pa0, xb0, a00, 0, 0, 0);
    a01 = __builtin_amdgcn_mfma_f32_16x16x32_bf16(pa0, xb1, a01, 0, 0, 0);
    a02 = __builtin_amdgcn_mfma_f32_16x16x32_bf16(pa0, xb2, a02, 0, 0, 0);
    a03 = __builtin_amdgcn_mfma_f32_16x16x32_bf16(pa0, xb3, a03, 0, 0, 0);
    a10 = __builtin_amdgcn_mfma_f32_16x16x32_bf16(pa1, xb0, a10, 0, 0, 0);
    a11 = __builtin_amdgcn_mfma_f32_16x16x32_bf16(pa1, xb1, a11, 0, 0, 0);
    a12 = __builtin_amdgcn_mfma_f32_16x16x32_bf16(pa1, xb2, a12, 0, 0, 0);
    a13 = __builtin_amdgcn_mfma_f32_16x16x32_bf16(pa1, xb3, a13, 0, 0, 0);

    xb0 = nb0; xb1 = nb1; xb2 = nb2; xb3 = nb3;
    sa = na; sb = nbb;
    c += 4;
  }

  // Z: sum the 4 k-group lanes of each row
  zz0 += __shfl_xor(zz0, 16, 64);
  zz0 += __shfl_xor(zz0, 32, 64);
  zz1 += __shfl_xor(zz1, 16, 64);
  zz1 += __shfl_xor(zz1, 32, 64);
  if (lane < 16) {
    zt[w][arow] = zz0;
    zt[w][16 + arow] = zz1;
  }

  // C/D frags -> LDS: row = grp*4+reg (+16 for frag1), col = dt*16 + arow
#pragma unroll
  for (int reg = 0; reg < 4; ++reg) {
    accT[w][grp * 4 + reg][0 * 16 + arow] = a00[reg];
    accT[w][grp * 4 + reg][1 * 16 + arow] = a01[reg];
    accT[w][grp * 4 + reg][2 * 16 + arow] = a02[reg];
    accT[w][grp * 4 + reg][3 * 16 + arow] = a03[reg];
    accT[w][16 + grp * 4 + reg][0 * 16 + arow] = a10[reg];
    accT[w][16 + grp * 4 + reg][1 * 16 + arow] = a11[reg];
    accT[w][16 + grp * 4 + reg][2 * 16 + arow] = a12[reg];
    accT[w][16 + grp * 4 + reg][3 * 16 + arow] = a13[reg];
  }
  __syncthreads();

#pragma unroll
  for (int k = 0; k < 8; ++k) {
    const int r = w * 8 + k;
    const float s = accT[0][r][lane] + accT[1][r][lane] + accT[2][r][lane] + accT[3][r][lane];
    const float z = zt[0][r] + zt[1][r] + zt[2][r] + zt[3][r];
    out[(size_t)(ibase + r) * D + lane] = s / z;
  }
}

extern "C" void kernel_launch(void* const* d_in, const int* in_sizes, int n_in,
                              void* d_out, int out_size, void* d_ws, size_t ws_size,
                              hipStream_t stream) {
  const float* x = (const float*)d_in[0];   // 8192*64 f32
  const float* W = (const float*)d_in[1];   // 64*64
  const float* b = (const float*)d_in[2];   // 64
  const float* a = (const float*)d_in[3];   // 128

  // ws: s1[8192] | s2[8192] | blockmax[256] | @1MB: xf (1MB bf16 frags)
  float* s1 = (float*)d_ws;
  float* s2 = s1 + N;
  float* blockmax = s2 + N;
  bf16x8* xf = (bf16x8*)((char*)d_ws + (1u << 20));
  float* out = (float*)d_out;

  gat_prep<<<N / PB, 256, 0, stream>>>(x, W, b, a, s1, s2, blockmax, xf);
  gat_main<<<N / RB, 256, 0, stream>>>(xf, s1, s2, blockmax, out);
}